// Round 11
// baseline (204.375 us; speedup 1.0000x reference)
//
#include <hip/hip_runtime.h>
#include <math.h>
#include <stdint.h>

#define B_    2
#define T_    2048
#define C_    2048
#define NH_   16
#define G_    4
#define HS_   128
#define WIN_  512
#define NQKV_ 3072
#define M_    4096
#define SCALE_ 0.08838834764831845f

typedef __attribute__((ext_vector_type(8))) __bf16 bf16x8;
typedef __attribute__((ext_vector_type(4))) float f32x4;
typedef unsigned short u16;

static __device__ __forceinline__ u16 f2bf(float f) {
  union { float f; unsigned u; } v; v.f = f;
  unsigned r = v.u + 0x7fffu + ((v.u >> 16) & 1u);
  return (u16)(r >> 16);
}
static __device__ __forceinline__ float bf2f(u16 h) {
  union { unsigned u; float f; } v; v.u = ((unsigned)h) << 16; return v.f;
}
static __device__ __forceinline__ bf16x8 ldg8(const u16* p) {
  return *(const bf16x8*)(const void*)p;
}

// ---------------- fused prep: x->bf16  ||  Wqkv^T  ||  Wproj^T ----------------
__global__ void prep_all(const float* __restrict__ x, const float* __restrict__ Wqkv,
                         const float* __restrict__ Wproj,
                         u16* __restrict__ x_bf, u16* __restrict__ wqkv_t,
                         u16* __restrict__ wproj_t) {
  int blk = blockIdx.x;
  if (blk < 8192) {
    int i = blk * 256 + threadIdx.x;
    float4 v = ((const float4*)x)[i];
    ushort4 o;
    o.x = f2bf(v.x); o.y = f2bf(v.y); o.z = f2bf(v.z); o.w = f2bf(v.w);
    ((ushort4*)x_bf)[i] = o;
    return;
  }
  __shared__ float tile[32][33];
  const float* in; u16* out; int R, Ccols, bx, by;
  if (blk < 8192 + 6144) {
    int idx = blk - 8192;
    in = Wqkv; out = wqkv_t; R = 2048; Ccols = 3072;
    bx = idx % 96; by = idx / 96;
  } else {
    int idx = blk - 14336;
    in = Wproj; out = wproj_t; R = 2048; Ccols = 2048;
    bx = idx & 63; by = idx >> 6;
  }
  int c0 = bx * 32, r0 = by * 32;
  int tx = threadIdx.x & 31, ty = threadIdx.x >> 5;
#pragma unroll
  for (int i = 0; i < 32; i += 8)
    tile[ty + i][tx] = in[(size_t)(r0 + ty + i) * Ccols + c0 + tx];
  __syncthreads();
#pragma unroll
  for (int i = 0; i < 32; i += 8)
    out[(size_t)(c0 + ty + i) * R + r0 + tx] = f2bf(tile[tx][ty + i]);
}

// ---------------- transpose bf16 v (per b: T x 512 -> 512 x T) ----------------
__global__ void transpose_v16(const u16* __restrict__ in, u16* __restrict__ out) {
  __shared__ u16 tile[32][33];
  int b = blockIdx.z;
  int c0 = blockIdx.x * 32, t0 = blockIdx.y * 32;
  int tx = threadIdx.x & 31, ty = threadIdx.x >> 5;
  const u16* src = in + (size_t)b * T_ * (G_*HS_);
  u16* dst = out + (size_t)b * (G_*HS_) * T_;
#pragma unroll
  for (int i = 0; i < 32; i += 8)
    tile[ty + i][tx] = src[(size_t)(t0 + ty + i) * (G_*HS_) + c0 + tx];
  __syncthreads();
#pragma unroll
  for (int i = 0; i < 32; i += 8)
    dst[(size_t)(c0 + ty + i) * T_ + t0 + tx] = tile[tx][ty + i];
}

// ---------------- GEMM: C[M][N] = A[M][K] * Bt[N][K]^T  (bf16 MFMA, m97-style) ----
// 128x128 tile, 4 waves. Known-good: qkv 65.0 us (790 TF), proj ~43 us.
// Do NOT: XCD-swizzle (r7: FETCH 57->72MB), 256^2 8-phase (r4: grid underfill).
template<int N, int K, int OUTBF>
__global__ __launch_bounds__(256)
void gemm_bt(const u16* __restrict__ A, const u16* __restrict__ Bt,
             u16* __restrict__ Cb, float* __restrict__ Cf) {
  __shared__ u16 lA[128 * 32];
  __shared__ u16 lB[128 * 32];
  const int m0 = blockIdx.x * 128;
  const int n0 = blockIdx.y * 128;
  const int lane = threadIdx.x & 63;
  const int wave = threadIdx.x >> 6;
  const int wr = (wave >> 1) * 64, wc = (wave & 1) * 64;
  const int fr = lane & 15, fk = (lane >> 4) * 8;
  const int srow = lane >> 2;
  const int scol = (lane & 3) * 8;
  f32x4 acc[4][4] = {};
  for (int k0 = 0; k0 < K; k0 += 32) {
#pragma unroll
    for (int c = 0; c < 2; ++c) {
      int chunk = wave * 2 + c;
      int row = chunk * 16 + srow;
      __builtin_amdgcn_global_load_lds(
          (__attribute__((address_space(1))) void*)(A + (size_t)(m0 + row) * K + k0 + scol),
          (__attribute__((address_space(3))) void*)(lA + chunk * 512), 16, 0, 0);
      __builtin_amdgcn_global_load_lds(
          (__attribute__((address_space(1))) void*)(Bt + (size_t)(n0 + row) * K + k0 + scol),
          (__attribute__((address_space(3))) void*)(lB + chunk * 512), 16, 0, 0);
    }
    __syncthreads();
    bf16x8 af[4], bb[4];
#pragma unroll
    for (int i = 0; i < 4; ++i) {
      af[i] = ldg8(lA + (wr + i * 16 + fr) * 32 + fk);
      bb[i] = ldg8(lB + (wc + i * 16 + fr) * 32 + fk);
    }
#pragma unroll
    for (int i = 0; i < 4; ++i)
#pragma unroll
      for (int j = 0; j < 4; ++j)
        acc[i][j] = __builtin_amdgcn_mfma_f32_16x16x32_bf16(af[i], bb[j], acc[i][j], 0, 0, 0);
    __syncthreads();
  }
  const int orow = m0 + wr + (lane >> 4) * 4;
  const int ocol = n0 + wc + fr;
#pragma unroll
  for (int i = 0; i < 4; ++i)
#pragma unroll
    for (int j = 0; j < 4; ++j)
#pragma unroll
      for (int jj = 0; jj < 4; ++jj) {
        int r = orow + i * 16 + jj, cc = ocol + j * 16;
        if (OUTBF) Cb[(size_t)r * N + cc] = f2bf(acc[i][j][jj]);
        else       Cf[(size_t)r * N + cc] = acc[i][j][jj];
      }
}

// ---------------- fused conv: q (rope+scale) || k (rope) || v — 8-wide ------
__global__ void conv_all(const u16* __restrict__ qkv, const float* __restrict__ qw,
                         const float* __restrict__ kw, const float* __restrict__ vw,
                         const float* __restrict__ cosT, const float* __restrict__ sinT,
                         u16* __restrict__ qout, u16* __restrict__ kout,
                         u16* __restrict__ vtmp) {
  int blk = blockIdx.x;
  const bf16x8 z8 = {};
  if (blk < 2048) {
    int tid = blk * 256 + threadIdx.x;
    int d8 = (tid & 7) << 3;
    int h  = (tid >> 3) & 15;
    int bt = tid >> 7;
    int t  = bt & (T_ - 1);
    int g = h >> 2, s = h & 3;
    int col = (g * 6 + s) * 128 + d8;
    const u16* p = qkv + (size_t)bt * NQKV_ + col;
    bf16x8 lo[4], hi[4];
#pragma unroll
    for (int k = 0; k < 4; ++k) {
      if (t + k >= 3) {
        long off = (long)(k - 3) * NQKV_;
        lo[k] = ldg8(p + off);
        hi[k] = ldg8(p + off + 64);
      } else { lo[k] = z8; hi[k] = z8; }
    }
    union { u16 a[8]; bf16x8 v; } olo, ohi;
#pragma unroll
    for (int j = 0; j < 8; ++j) {
      float4 wl = *(const float4*)(qw + (size_t)(h * 128 + d8 + j) * 4);
      float4 wh = *(const float4*)(qw + (size_t)(h * 128 + 64 + d8 + j) * 4);
      float a1 = wl.x * (float)lo[0][j] + wl.y * (float)lo[1][j] +
                 wl.z * (float)lo[2][j] + wl.w * (float)lo[3][j];
      float a2 = wh.x * (float)hi[0][j] + wh.y * (float)hi[1][j] +
                 wh.z * (float)hi[2][j] + wh.w * (float)hi[3][j];
      a1 = a1 / (1.f + __expf(-a1));
      a2 = a2 / (1.f + __expf(-a2));
      float c = cosT[t * 64 + d8 + j], sn = sinT[t * 64 + d8 + j];
      olo.a[j] = f2bf((a1 * c - a2 * sn) * SCALE_);
      ohi.a[j] = f2bf((a1 * sn + a2 * c) * SCALE_);
    }
    u16* dst = qout + ((size_t)bt * NH_ + h) * HS_ + d8;
    *(bf16x8*)(dst) = olo.v;
    *(bf16x8*)(dst + 64) = ohi.v;
  } else {
    int tid = (blk - 2048) * 256 + threadIdx.x;
    int idx = tid & 63;
    int bt  = tid >> 6;
    int t   = bt & (T_ - 1);
    int isv = idx >> 5;
    int g   = (idx >> 3) & 3;
    int d8  = (idx & 7) << 3;
    int col = (g * 6 + 4 + isv) * 128 + d8;
    const float* w = isv ? vw : kw;
    const u16* p = qkv + (size_t)bt * NQKV_ + col;
    bf16x8 lo[4], hi[4];
#pragma unroll
    for (int k = 0; k < 4; ++k) {
      if (t + k >= 3) {
        long off = (long)(k - 3) * NQKV_;
        lo[k] = ldg8(p + off);
        hi[k] = ldg8(p + off + 64);
      } else { lo[k] = z8; hi[k] = z8; }
    }
    float a1[8], a2[8];
#pragma unroll
    for (int j = 0; j < 8; ++j) {
      float4 wl = *(const float4*)(w + (size_t)(g * 128 + d8 + j) * 4);
      float4 wh = *(const float4*)(w + (size_t)(g * 128 + 64 + d8 + j) * 4);
      float x1 = wl.x * (float)lo[0][j] + wl.y * (float)lo[1][j] +
                 wl.z * (float)lo[2][j] + wl.w * (float)lo[3][j];
      float x2 = wh.x * (float)hi[0][j] + wh.y * (float)hi[1][j] +
                 wh.z * (float)hi[2][j] + wh.w * (float)hi[3][j];
      a1[j] = x1 / (1.f + __expf(-x1));
      a2[j] = x2 / (1.f + __expf(-x2));
    }
    union { u16 a[8]; bf16x8 v; } olo, ohi;
    if (isv == 0) {
#pragma unroll
      for (int j = 0; j < 8; ++j) {
        float c = cosT[t * 64 + d8 + j], sn = sinT[t * 64 + d8 + j];
        olo.a[j] = f2bf(a1[j] * c - a2[j] * sn);
        ohi.a[j] = f2bf(a1[j] * sn + a2[j] * c);
      }
      u16* dst = kout + ((size_t)bt * G_ + g) * HS_ + d8;
      *(bf16x8*)(dst) = olo.v;
      *(bf16x8*)(dst + 64) = ohi.v;
    } else {
#pragma unroll
      for (int j = 0; j < 8; ++j) {
        olo.a[j] = f2bf(a1[j]);
        ohi.a[j] = f2bf(a2[j]);
      }
      u16* dst = vtmp + ((size_t)bt * G_ + g) * HS_ + d8;
      *(bf16x8*)(dst) = olo.v;
      *(bf16x8*)(dst + 64) = ohi.v;
    }
  }
}

// ---------------- sliding-window GQA flash attention (v8) ----------------
// round-6 structure (dbuf 80KB, 2 blocks/CU) + T4 counted-vmcnt barriers:
// replace __syncthreads (vmcnt(0) drain of the just-issued prefetch) with
//   s_barrier                  // all waves done reading buf cur^1 (tile t-1)
//   stage(cur^1, tile t+1)     // issue 8 loads
//   s_waitcnt vmcnt(8)         // tile-t loads (one iteration old) landed
//   s_barrier                  // all waves' tile-t data visible
//   compute(cur)
// vmcnt never drains to 0 in steady state; buffer safety by barrier order.
// Do NOT: 3-buf 112KB (r8: 1 blk/CU, -30us), direct-V (r9: 388MB HBM).
__global__ __launch_bounds__(256, 2)
void attn_swin(const u16* __restrict__ qbf, const u16* __restrict__ kbf,
               const u16* __restrict__ vt, u16* __restrict__ ybf) {
  __shared__ __align__(16) char kls[2][16384];  // [64 s][256 B] swizzled
  __shared__ __align__(16) char vls[2][16384];  // [128 d][128 B] swizzled
  __shared__ __align__(16) char pls[4][4096];   // per-wave P [32 q][128 B] swizzled
  const int lane = threadIdx.x & 63;
  const int wave = threadIdx.x >> 6;
  const int btile = blockIdx.x & 15;
  const int h  = (blockIdx.x >> 4) & 15;
  const int b  = blockIdx.x >> 8;
  const int g  = h >> 2;
  const int t0b = btile << 7;
  const int t0w = t0b + wave * 32;
  const int fr = lane & 15;
  const int hi = lane >> 4;
  const int fko = hi * 8;
  char* pl = pls[wave];
  const int swz = (fr & 7) << 4;

  const int krow_l = (lane >> 4);
  const int kcb    = (lane & 15) * 16;
  const int vrow_l = (lane >> 3);
  const int vcb    = (lane & 7) * 16;

  bf16x8 qf[2][4];
#pragma unroll
  for (int qh = 0; qh < 2; ++qh) {
    const u16* qb = qbf + ((size_t)((b * T_ + t0w + qh * 16 + fr) * NH_ + h)) * HS_ + fko;
#pragma unroll
    for (int kc = 0; kc < 4; ++kc) qf[qh][kc] = ldg8(qb + kc * 32);
  }

  int sbeg = t0b - (WIN_ - 1); if (sbeg < 0) sbeg = 0; sbeg &= ~63;
  const int nt = (t0b + 128 - sbeg) >> 6;

  const char* kgbase = (const char*)kbf + (((size_t)(b * T_) * G_ + g) * HS_) * 2;
  const char* vgbase = (const char*)vt + ((size_t)(b * (G_*HS_) + g * HS_)) * T_ * 2;

  auto stage = [&](int bufi, int s0) {
    char* kb = kls[bufi]; char* vb = vls[bufi];
#pragma unroll
    for (int c = 0; c < 4; ++c) {
      int i = wave * 4 + c;
      {
        int row = i * 4 + krow_l;
        int scb = kcb ^ ((row & 7) << 4);
        const char* src = kgbase + (size_t)(s0 + row) * (G_*HS_*2) + scb;
        __builtin_amdgcn_global_load_lds(
            (__attribute__((address_space(1))) void*)src,
            (__attribute__((address_space(3))) void*)(kb + i * 1024), 16, 0, 0);
      }
      {
        int row = i * 8 + vrow_l;
        int scb = vcb ^ ((row & 7) << 4);
        const char* src = vgbase + (size_t)row * (T_*2) + (size_t)s0 * 2 + scb;
        __builtin_amdgcn_global_load_lds(
            (__attribute__((address_space(1))) void*)src,
            (__attribute__((address_space(3))) void*)(vb + i * 1024), 16, 0, 0);
      }
    }
  };

  f32x4 acc_o[2][8];
#pragma unroll
  for (int qh = 0; qh < 2; ++qh)
#pragma unroll
    for (int n = 0; n < 8; ++n) acc_o[qh][n] = (f32x4){0.f, 0.f, 0.f, 0.f};
  float m_r[2] = {-1e30f, -1e30f}, l_r[2] = {0.f, 0.f};

  stage(0, sbeg);   // tile 0 in flight (8 loads/wave)
  int cur = 0;

  for (int t = 0; t < nt; ++t) {
    int s0 = sbeg + (t << 6);
    // [1] all waves finished reading buf cur^1 (tile t-1) -> safe to overwrite
    asm volatile("" ::: "memory");
    __builtin_amdgcn_s_barrier();
    asm volatile("" ::: "memory");
    if (t + 1 < nt) {
      stage(cur ^ 1, s0 + 64);                       // 8 more loads in flight
      asm volatile("s_waitcnt vmcnt(8)" ::: "memory"); // our tile-t loads landed
    } else {
      asm volatile("s_waitcnt vmcnt(0)" ::: "memory"); // tail drain
    }
    // [2] every wave's tile-t loads landed -> LDS tile t complete
    __builtin_amdgcn_s_barrier();
    asm volatile("" ::: "memory");

    const char* kb = kls[cur];
    const char* vb = vls[cur];

    // ---- QK^T (swapped): kf shared across both Q-halves ----
    f32x4 st[2][4];
#pragma unroll
    for (int qh = 0; qh < 2; ++qh)
#pragma unroll
      for (int c = 0; c < 4; ++c) st[qh][c] = (f32x4){0.f, 0.f, 0.f, 0.f};
    __builtin_amdgcn_s_setprio(1);
#pragma unroll
    for (int c = 0; c < 4; ++c) {
      int row = c * 16 + fr;
#pragma unroll
      for (int kc = 0; kc < 4; ++kc) {
        bf16x8 kf = *(const bf16x8*)(kb + row * 256 + ((kc * 64 + hi * 16) ^ swz));
        st[0][c] = __builtin_amdgcn_mfma_f32_16x16x32_bf16(kf, qf[0][kc], st[0][c], 0, 0, 0);
        st[1][c] = __builtin_amdgcn_mfma_f32_16x16x32_bf16(kf, qf[1][kc], st[1][c], 0, 0, 0);
      }
    }
    __builtin_amdgcn_s_setprio(0);

    // ---- per-qhalf: mask, max, exp, P write, defer-max rescale ----
#pragma unroll
    for (int qh = 0; qh < 2; ++qh) {
      int qr = t0w + qh * 16 + fr;
      float tmax = -1e30f;
#pragma unroll
      for (int c = 0; c < 4; ++c)
#pragma unroll
        for (int j = 0; j < 4; ++j) {
          int key = s0 + c * 16 + hi * 4 + j;
          int dlt = qr - key;
          float x = (dlt >= 0 && dlt < WIN_) ? st[qh][c][j] : -1e30f;
          st[qh][c][j] = x;
          tmax = fmaxf(tmax, x);
        }
      tmax = fmaxf(tmax, __shfl_xor(tmax, 16, 64));
      tmax = fmaxf(tmax, __shfl_xor(tmax, 32, 64));
      float fac = 1.f;
      bool need = !__all(tmax <= m_r[qh] + 8.f);   // T13 defer-max
      if (need) {
        float mn = fmaxf(m_r[qh], tmax);
        fac = __expf(m_r[qh] - mn);
        m_r[qh] = mn;
      }
      float ps = 0.f;
#pragma unroll
      for (int c = 0; c < 4; ++c) {
        union { ushort4 u4; __bf16 hh[4]; } pk;
#pragma unroll
        for (int j = 0; j < 4; ++j) {
          float p = (st[qh][c][j] > -1e29f) ? __expf(st[qh][c][j] - m_r[qh]) : 0.f;
          ps += p;
          pk.hh[j] = (__bf16)p;
        }
        *(ushort4*)(pl + (qh * 16 + fr) * 128 + ((c * 32 + hi * 8) ^ swz)) = pk.u4;
      }
      ps += __shfl_xor(ps, 16, 64);
      ps += __shfl_xor(ps, 32, 64);
      l_r[qh] = l_r[qh] * fac + ps;
      if (need) {
        float fq0 = __shfl(fac, hi * 4 + 0, 64);
        float fq1 = __shfl(fac, hi * 4 + 1, 64);
        float fq2 = __shfl(fac, hi * 4 + 2, 64);
        float fq3 = __shfl(fac, hi * 4 + 3, 64);
#pragma unroll
        for (int n = 0; n < 8; ++n) {
          acc_o[qh][n][0] *= fq0; acc_o[qh][n][1] *= fq1;
          acc_o[qh][n][2] *= fq2; acc_o[qh][n][3] *= fq3;
        }
      }
    }

    // ---- PV: vf shared across both Q-halves ----
#pragma unroll
    for (int ch = 0; ch < 2; ++ch) {
      bf16x8 pa0 = *(const bf16x8*)(pl + fr * 128 + ((ch * 64 + hi * 16) ^ swz));
      bf16x8 pa1 = *(const bf16x8*)(pl + (16 + fr) * 128 + ((ch * 64 + hi * 16) ^ swz));
      __builtin_amdgcn_s_setprio(1);
#pragma unroll
      for (int n = 0; n < 8; ++n) {
        int row = n * 16 + fr;
        bf16x8 vf = *(const bf16x8*)(vb + row * 128 + ((ch * 64 + hi * 16) ^ swz));
        acc_o[0][n] = __builtin_amdgcn_mfma_f32_16x16x32_bf16(pa0, vf, acc_o[0][n], 0, 0, 0);
        acc_o[1][n] = __builtin_amdgcn_mfma_f32_16x16x32_bf16(pa1, vf, acc_o[1][n], 0, 0, 0);
      }
      __builtin_amdgcn_s_setprio(0);
    }
    cur ^= 1;
  }

  // ---- epilogue ----
#pragma unroll
  for (int qh = 0; qh < 2; ++qh) {
    float inv = 1.f / l_r[qh];
    float iq[4];
#pragma unroll
    for (int j = 0; j < 4; ++j) iq[j] = __shfl(inv, hi * 4 + j, 64);
#pragma unroll
    for (int n = 0; n < 8; ++n)
#pragma unroll
      for (int jj = 0; jj < 4; ++jj) {
        int t = t0w + qh * 16 + hi * 4 + jj;
        ybf[((size_t)(b * T_ + t)) * (NH_*HS_) + h * HS_ + n * 16 + fr] =
            f2bf(acc_o[qh][n][jj] * iq[jj]);
      }
  }
}

extern "C" void kernel_launch(void* const* d_in, const int* in_sizes, int n_in,
                              void* d_out, int out_size, void* d_ws, size_t ws_size,
                              hipStream_t stream) {
  (void)in_sizes; (void)n_in; (void)out_size;
  const float* x     = (const float*)d_in[0];
  const float* Wqkv  = (const float*)d_in[1];
  const float* Wproj = (const float*)d_in[2];
  const float* qw    = (const float*)d_in[3];
  const float* kw    = (const float*)d_in[4];
  const float* vw    = (const float*)d_in[5];
  const float* cosT  = (const float*)d_in[6];
  const float* sinT  = (const float*)d_in[7];
  float* out = (float*)d_out;
  char* ws = (char*)d_ws;

  // workspace layout (bytes)
  u16* x_bf    = (u16*)(ws + 0);          // 16,777,216
  u16* wqkv_t  = (u16*)(ws + 16777216);   // 12,582,912
  u16* wproj_t = (u16*)(ws + 29360128);   //  8,388,608
  u16* qkv_bf  = (u16*)(ws + 37748736);   // 25,165,824
  u16* q_bf    = (u16*)(ws + 62914560);   // 16,777,216
  u16* k_bf    = (u16*)(ws + 79691776);   //  4,194,304
  u16* v_tmp   = (u16*)(ws + 83886080);   //  4,194,304
  u16* v_t     = (u16*)(ws + 88080384);   //  4,194,304
  u16* y_bf    = (u16*)(ws + 92274688);   // 16,777,216
  if (ws_size < (size_t)109051904) return;

  prep_all<<<18432, 256, 0, stream>>>(x, Wqkv, Wproj, x_bf, wqkv_t, wproj_t);
  gemm_bt<3072, 2048, 1><<<dim3(32, 24), 256, 0, stream>>>(x_bf, wqkv_t, qkv_bf, nullptr);
  conv_all<<<3072, 256, 0, stream>>>(qkv_bf, qw, kw, vw, cosT, sinT, q_bf, k_bf, v_tmp);
  transpose_v16<<<dim3(16, 64, 2), 256, 0, stream>>>(v_tmp, v_t);
  attn_swin<<<512, 256, 0, stream>>>(q_bf, k_bf, v_t, y_bf);
  gemm_bt<2048, 2048, 0><<<dim3(32, 16), 256, 0, stream>>>(y_bf, wproj_t, nullptr, out);
}

// Round 12
// 202.662 us; speedup vs baseline: 1.0085x; 1.0085x over previous
//
#include <hip/hip_runtime.h>
#include <math.h>
#include <stdint.h>

#define B_    2
#define T_    2048
#define C_    2048
#define NH_   16
#define G_    4
#define HS_   128
#define WIN_  512
#define NQKV_ 3072
#define M_    4096
#define SCALE_ 0.08838834764831845f

typedef __attribute__((ext_vector_type(8))) __bf16 bf16x8;
typedef __attribute__((ext_vector_type(4))) float f32x4;
typedef unsigned short u16;

static __device__ __forceinline__ u16 f2bf(float f) {
  union { float f; unsigned u; } v; v.f = f;
  unsigned r = v.u + 0x7fffu + ((v.u >> 16) & 1u);
  return (u16)(r >> 16);
}
static __device__ __forceinline__ float bf2f(u16 h) {
  union { unsigned u; float f; } v; v.u = ((unsigned)h) << 16; return v.f;
}
static __device__ __forceinline__ bf16x8 ldg8(const u16* p) {
  return *(const bf16x8*)(const void*)p;
}

// ---------------- fused prep: x->bf16  ||  Wqkv^T  ||  Wproj^T ----------------
__global__ void prep_all(const float* __restrict__ x, const float* __restrict__ Wqkv,
                         const float* __restrict__ Wproj,
                         u16* __restrict__ x_bf, u16* __restrict__ wqkv_t,
                         u16* __restrict__ wproj_t) {
  int blk = blockIdx.x;
  if (blk < 8192) {
    int i = blk * 256 + threadIdx.x;
    float4 v = ((const float4*)x)[i];
    ushort4 o;
    o.x = f2bf(v.x); o.y = f2bf(v.y); o.z = f2bf(v.z); o.w = f2bf(v.w);
    ((ushort4*)x_bf)[i] = o;
    return;
  }
  __shared__ float tile[32][33];
  const float* in; u16* out; int R, Ccols, bx, by;
  if (blk < 8192 + 6144) {
    int idx = blk - 8192;
    in = Wqkv; out = wqkv_t; R = 2048; Ccols = 3072;
    bx = idx % 96; by = idx / 96;
  } else {
    int idx = blk - 14336;
    in = Wproj; out = wproj_t; R = 2048; Ccols = 2048;
    bx = idx & 63; by = idx >> 6;
  }
  int c0 = bx * 32, r0 = by * 32;
  int tx = threadIdx.x & 31, ty = threadIdx.x >> 5;
#pragma unroll
  for (int i = 0; i < 32; i += 8)
    tile[ty + i][tx] = in[(size_t)(r0 + ty + i) * Ccols + c0 + tx];
  __syncthreads();
#pragma unroll
  for (int i = 0; i < 32; i += 8)
    out[(size_t)(c0 + ty + i) * R + r0 + tx] = f2bf(tile[tx][ty + i]);
}

// ---------------- transpose bf16 v (per b: T x 512 -> 512 x T) ----------------
__global__ void transpose_v16(const u16* __restrict__ in, u16* __restrict__ out) {
  __shared__ u16 tile[32][33];
  int b = blockIdx.z;
  int c0 = blockIdx.x * 32, t0 = blockIdx.y * 32;
  int tx = threadIdx.x & 31, ty = threadIdx.x >> 5;
  const u16* src = in + (size_t)b * T_ * (G_*HS_);
  u16* dst = out + (size_t)b * (G_*HS_) * T_;
#pragma unroll
  for (int i = 0; i < 32; i += 8)
    tile[ty + i][tx] = src[(size_t)(t0 + ty + i) * (G_*HS_) + c0 + tx];
  __syncthreads();
#pragma unroll
  for (int i = 0; i < 32; i += 8)
    dst[(size_t)(c0 + ty + i) * T_ + t0 + tx] = tile[tx][ty + i];
}

// ---------------- GEMM: C[M][N] = A[M][K] * Bt[N][K]^T  (bf16 MFMA, m97-style) ----
// 128x128 tile, 4 waves. Known-good: qkv 65.0 us (790 TF), proj ~43 us.
// Do NOT: XCD-swizzle (r7: FETCH 57->72MB), 256^2 8-phase (r4: grid underfill).
template<int N, int K, int OUTBF>
__global__ __launch_bounds__(256)
void gemm_bt(const u16* __restrict__ A, const u16* __restrict__ Bt,
             u16* __restrict__ Cb, float* __restrict__ Cf) {
  __shared__ u16 lA[128 * 32];
  __shared__ u16 lB[128 * 32];
  const int m0 = blockIdx.x * 128;
  const int n0 = blockIdx.y * 128;
  const int lane = threadIdx.x & 63;
  const int wave = threadIdx.x >> 6;
  const int wr = (wave >> 1) * 64, wc = (wave & 1) * 64;
  const int fr = lane & 15, fk = (lane >> 4) * 8;
  const int srow = lane >> 2;
  const int scol = (lane & 3) * 8;
  f32x4 acc[4][4] = {};
  for (int k0 = 0; k0 < K; k0 += 32) {
#pragma unroll
    for (int c = 0; c < 2; ++c) {
      int chunk = wave * 2 + c;
      int row = chunk * 16 + srow;
      __builtin_amdgcn_global_load_lds(
          (__attribute__((address_space(1))) void*)(A + (size_t)(m0 + row) * K + k0 + scol),
          (__attribute__((address_space(3))) void*)(lA + chunk * 512), 16, 0, 0);
      __builtin_amdgcn_global_load_lds(
          (__attribute__((address_space(1))) void*)(Bt + (size_t)(n0 + row) * K + k0 + scol),
          (__attribute__((address_space(3))) void*)(lB + chunk * 512), 16, 0, 0);
    }
    __syncthreads();
    bf16x8 af[4], bb[4];
#pragma unroll
    for (int i = 0; i < 4; ++i) {
      af[i] = ldg8(lA + (wr + i * 16 + fr) * 32 + fk);
      bb[i] = ldg8(lB + (wc + i * 16 + fr) * 32 + fk);
    }
#pragma unroll
    for (int i = 0; i < 4; ++i)
#pragma unroll
      for (int j = 0; j < 4; ++j)
        acc[i][j] = __builtin_amdgcn_mfma_f32_16x16x32_bf16(af[i], bb[j], acc[i][j], 0, 0, 0);
    __syncthreads();
  }
  const int orow = m0 + wr + (lane >> 4) * 4;
  const int ocol = n0 + wc + fr;
#pragma unroll
  for (int i = 0; i < 4; ++i)
#pragma unroll
    for (int j = 0; j < 4; ++j)
#pragma unroll
      for (int jj = 0; jj < 4; ++jj) {
        int r = orow + i * 16 + jj, cc = ocol + j * 16;
        if (OUTBF) Cb[(size_t)r * N + cc] = f2bf(acc[i][j][jj]);
        else       Cf[(size_t)r * N + cc] = acc[i][j][jj];
      }
}

// ---------------- fused conv: q (rope+scale) || k (rope) || v — 8-wide ------
__global__ void conv_all(const u16* __restrict__ qkv, const float* __restrict__ qw,
                         const float* __restrict__ kw, const float* __restrict__ vw,
                         const float* __restrict__ cosT, const float* __restrict__ sinT,
                         u16* __restrict__ qout, u16* __restrict__ kout,
                         u16* __restrict__ vtmp) {
  int blk = blockIdx.x;
  const bf16x8 z8 = {};
  if (blk < 2048) {
    int tid = blk * 256 + threadIdx.x;
    int d8 = (tid & 7) << 3;
    int h  = (tid >> 3) & 15;
    int bt = tid >> 7;
    int t  = bt & (T_ - 1);
    int g = h >> 2, s = h & 3;
    int col = (g * 6 + s) * 128 + d8;
    const u16* p = qkv + (size_t)bt * NQKV_ + col;
    bf16x8 lo[4], hi[4];
#pragma unroll
    for (int k = 0; k < 4; ++k) {
      if (t + k >= 3) {
        long off = (long)(k - 3) * NQKV_;
        lo[k] = ldg8(p + off);
        hi[k] = ldg8(p + off + 64);
      } else { lo[k] = z8; hi[k] = z8; }
    }
    union { u16 a[8]; bf16x8 v; } olo, ohi;
#pragma unroll
    for (int j = 0; j < 8; ++j) {
      float4 wl = *(const float4*)(qw + (size_t)(h * 128 + d8 + j) * 4);
      float4 wh = *(const float4*)(qw + (size_t)(h * 128 + 64 + d8 + j) * 4);
      float a1 = wl.x * (float)lo[0][j] + wl.y * (float)lo[1][j] +
                 wl.z * (float)lo[2][j] + wl.w * (float)lo[3][j];
      float a2 = wh.x * (float)hi[0][j] + wh.y * (float)hi[1][j] +
                 wh.z * (float)hi[2][j] + wh.w * (float)hi[3][j];
      a1 = a1 / (1.f + __expf(-a1));
      a2 = a2 / (1.f + __expf(-a2));
      float c = cosT[t * 64 + d8 + j], sn = sinT[t * 64 + d8 + j];
      olo.a[j] = f2bf((a1 * c - a2 * sn) * SCALE_);
      ohi.a[j] = f2bf((a1 * sn + a2 * c) * SCALE_);
    }
    u16* dst = qout + ((size_t)bt * NH_ + h) * HS_ + d8;
    *(bf16x8*)(dst) = olo.v;
    *(bf16x8*)(dst + 64) = ohi.v;
  } else {
    int tid = (blk - 2048) * 256 + threadIdx.x;
    int idx = tid & 63;
    int bt  = tid >> 6;
    int t   = bt & (T_ - 1);
    int isv = idx >> 5;
    int g   = (idx >> 3) & 3;
    int d8  = (idx & 7) << 3;
    int col = (g * 6 + 4 + isv) * 128 + d8;
    const float* w = isv ? vw : kw;
    const u16* p = qkv + (size_t)bt * NQKV_ + col;
    bf16x8 lo[4], hi[4];
#pragma unroll
    for (int k = 0; k < 4; ++k) {
      if (t + k >= 3) {
        long off = (long)(k - 3) * NQKV_;
        lo[k] = ldg8(p + off);
        hi[k] = ldg8(p + off + 64);
      } else { lo[k] = z8; hi[k] = z8; }
    }
    float a1[8], a2[8];
#pragma unroll
    for (int j = 0; j < 8; ++j) {
      float4 wl = *(const float4*)(w + (size_t)(g * 128 + d8 + j) * 4);
      float4 wh = *(const float4*)(w + (size_t)(g * 128 + 64 + d8 + j) * 4);
      float x1 = wl.x * (float)lo[0][j] + wl.y * (float)lo[1][j] +
                 wl.z * (float)lo[2][j] + wl.w * (float)lo[3][j];
      float x2 = wh.x * (float)hi[0][j] + wh.y * (float)hi[1][j] +
                 wh.z * (float)hi[2][j] + wh.w * (float)hi[3][j];
      a1[j] = x1 / (1.f + __expf(-x1));
      a2[j] = x2 / (1.f + __expf(-x2));
    }
    union { u16 a[8]; bf16x8 v; } olo, ohi;
    if (isv == 0) {
#pragma unroll
      for (int j = 0; j < 8; ++j) {
        float c = cosT[t * 64 + d8 + j], sn = sinT[t * 64 + d8 + j];
        olo.a[j] = f2bf(a1[j] * c - a2[j] * sn);
        ohi.a[j] = f2bf(a1[j] * sn + a2[j] * c);
      }
      u16* dst = kout + ((size_t)bt * G_ + g) * HS_ + d8;
      *(bf16x8*)(dst) = olo.v;
      *(bf16x8*)(dst + 64) = ohi.v;
    } else {
#pragma unroll
      for (int j = 0; j < 8; ++j) {
        olo.a[j] = f2bf(a1[j]);
        ohi.a[j] = f2bf(a2[j]);
      }
      u16* dst = vtmp + ((size_t)bt * G_ + g) * HS_ + d8;
      *(bf16x8*)(dst) = olo.v;
      *(bf16x8*)(dst + 64) = ohi.v;
    }
  }
}

// ---------------- sliding-window GQA flash attention (v9) ----------------
// r11 structure (dbuf 80KB, 2 blocks/CU, counted-vmcnt barriers) + interior-
// tile fast path: tiles fully inside the window for all 32 wave queries
// (s0+63<=t0w && s0>=t0w-480, wave-uniform) skip the 64 cndmask/cmp mask ops
// and the 64 exp gates per tile. Partial tiles keep the gated path (the gate
// is REQUIRED there: ungated exp with m_r=-1e30 on an all-masked first-tile
// row would yield p=1 — verified trap).
// Do NOT: 3-buf 112KB (r8), direct-V (r9), XCD swz (r7).
__global__ __launch_bounds__(256, 2)
void attn_swin(const u16* __restrict__ qbf, const u16* __restrict__ kbf,
               const u16* __restrict__ vt, u16* __restrict__ ybf) {
  __shared__ __align__(16) char kls[2][16384];  // [64 s][256 B] swizzled
  __shared__ __align__(16) char vls[2][16384];  // [128 d][128 B] swizzled
  __shared__ __align__(16) char pls[4][4096];   // per-wave P [32 q][128 B] swizzled
  const int lane = threadIdx.x & 63;
  const int wave = threadIdx.x >> 6;
  const int btile = blockIdx.x & 15;
  const int h  = (blockIdx.x >> 4) & 15;
  const int b  = blockIdx.x >> 8;
  const int g  = h >> 2;
  const int t0b = btile << 7;
  const int t0w = t0b + wave * 32;
  const int fr = lane & 15;
  const int hi = lane >> 4;
  const int fko = hi * 8;
  char* pl = pls[wave];
  const int swz = (fr & 7) << 4;

  const int krow_l = (lane >> 4);
  const int kcb    = (lane & 15) * 16;
  const int vrow_l = (lane >> 3);
  const int vcb    = (lane & 7) * 16;

  bf16x8 qf[2][4];
#pragma unroll
  for (int qh = 0; qh < 2; ++qh) {
    const u16* qb = qbf + ((size_t)((b * T_ + t0w + qh * 16 + fr) * NH_ + h)) * HS_ + fko;
#pragma unroll
    for (int kc = 0; kc < 4; ++kc) qf[qh][kc] = ldg8(qb + kc * 32);
  }

  int sbeg = t0b - (WIN_ - 1); if (sbeg < 0) sbeg = 0; sbeg &= ~63;
  const int nt = (t0b + 128 - sbeg) >> 6;

  const char* kgbase = (const char*)kbf + (((size_t)(b * T_) * G_ + g) * HS_) * 2;
  const char* vgbase = (const char*)vt + ((size_t)(b * (G_*HS_) + g * HS_)) * T_ * 2;

  auto stage = [&](int bufi, int s0) {
    char* kb = kls[bufi]; char* vb = vls[bufi];
#pragma unroll
    for (int c = 0; c < 4; ++c) {
      int i = wave * 4 + c;
      {
        int row = i * 4 + krow_l;
        int scb = kcb ^ ((row & 7) << 4);
        const char* src = kgbase + (size_t)(s0 + row) * (G_*HS_*2) + scb;
        __builtin_amdgcn_global_load_lds(
            (__attribute__((address_space(1))) void*)src,
            (__attribute__((address_space(3))) void*)(kb + i * 1024), 16, 0, 0);
      }
      {
        int row = i * 8 + vrow_l;
        int scb = vcb ^ ((row & 7) << 4);
        const char* src = vgbase + (size_t)row * (T_*2) + (size_t)s0 * 2 + scb;
        __builtin_amdgcn_global_load_lds(
            (__attribute__((address_space(1))) void*)src,
            (__attribute__((address_space(3))) void*)(vb + i * 1024), 16, 0, 0);
      }
    }
  };

  f32x4 acc_o[2][8];
#pragma unroll
  for (int qh = 0; qh < 2; ++qh)
#pragma unroll
    for (int n = 0; n < 8; ++n) acc_o[qh][n] = (f32x4){0.f, 0.f, 0.f, 0.f};
  float m_r[2] = {-1e30f, -1e30f}, l_r[2] = {0.f, 0.f};

  stage(0, sbeg);   // tile 0 in flight (8 loads/wave)
  int cur = 0;

  for (int t = 0; t < nt; ++t) {
    int s0 = sbeg + (t << 6);
    // [1] all waves finished reading buf cur^1 (tile t-1) -> safe to overwrite
    asm volatile("" ::: "memory");
    __builtin_amdgcn_s_barrier();
    asm volatile("" ::: "memory");
    if (t + 1 < nt) {
      stage(cur ^ 1, s0 + 64);                       // 8 more loads in flight
      asm volatile("s_waitcnt vmcnt(8)" ::: "memory"); // our tile-t loads landed
    } else {
      asm volatile("s_waitcnt vmcnt(0)" ::: "memory"); // tail drain
    }
    // [2] every wave's tile-t loads landed -> LDS tile t complete
    __builtin_amdgcn_s_barrier();
    asm volatile("" ::: "memory");

    const char* kb = kls[cur];
    const char* vb = vls[cur];

    // ---- QK^T (swapped): kf shared across both Q-halves ----
    f32x4 st[2][4];
#pragma unroll
    for (int qh = 0; qh < 2; ++qh)
#pragma unroll
      for (int c = 0; c < 4; ++c) st[qh][c] = (f32x4){0.f, 0.f, 0.f, 0.f};
    __builtin_amdgcn_s_setprio(1);
#pragma unroll
    for (int c = 0; c < 4; ++c) {
      int row = c * 16 + fr;
#pragma unroll
      for (int kc = 0; kc < 4; ++kc) {
        bf16x8 kf = *(const bf16x8*)(kb + row * 256 + ((kc * 64 + hi * 16) ^ swz));
        st[0][c] = __builtin_amdgcn_mfma_f32_16x16x32_bf16(kf, qf[0][kc], st[0][c], 0, 0, 0);
        st[1][c] = __builtin_amdgcn_mfma_f32_16x16x32_bf16(kf, qf[1][kc], st[1][c], 0, 0, 0);
      }
    }
    __builtin_amdgcn_s_setprio(0);

    // interior tile: every (q,s) pair valid for this wave's 32 queries
    const bool fullt = (s0 + 63 <= t0w) && (s0 >= t0w - 480);

    // ---- per-qhalf: mask, max, exp, P write, defer-max rescale ----
#pragma unroll
    for (int qh = 0; qh < 2; ++qh) {
      int qr = t0w + qh * 16 + fr;
      float tmax = -1e30f;
      if (fullt) {
#pragma unroll
        for (int c = 0; c < 4; ++c)
#pragma unroll
          for (int j = 0; j < 4; ++j) tmax = fmaxf(tmax, st[qh][c][j]);
      } else {
#pragma unroll
        for (int c = 0; c < 4; ++c)
#pragma unroll
          for (int j = 0; j < 4; ++j) {
            int key = s0 + c * 16 + hi * 4 + j;
            unsigned dlt = (unsigned)(qr - key);
            float x = (dlt < (unsigned)WIN_) ? st[qh][c][j] : -1e30f;
            st[qh][c][j] = x;
            tmax = fmaxf(tmax, x);
          }
      }
      tmax = fmaxf(tmax, __shfl_xor(tmax, 16, 64));
      tmax = fmaxf(tmax, __shfl_xor(tmax, 32, 64));
      float fac = 1.f;
      bool need = !__all(tmax <= m_r[qh] + 8.f);   // T13 defer-max
      if (need) {
        float mn = fmaxf(m_r[qh], tmax);
        fac = __expf(m_r[qh] - mn);
        m_r[qh] = mn;
      }
      float ps = 0.f;
      if (fullt) {
#pragma unroll
        for (int c = 0; c < 4; ++c) {
          union { ushort4 u4; __bf16 hh[4]; } pk;
#pragma unroll
          for (int j = 0; j < 4; ++j) {
            float p = __expf(st[qh][c][j] - m_r[qh]);   // no gate: all valid
            ps += p;
            pk.hh[j] = (__bf16)p;
          }
          *(ushort4*)(pl + (qh * 16 + fr) * 128 + ((c * 32 + hi * 8) ^ swz)) = pk.u4;
        }
      } else {
#pragma unroll
        for (int c = 0; c < 4; ++c) {
          union { ushort4 u4; __bf16 hh[4]; } pk;
#pragma unroll
          for (int j = 0; j < 4; ++j) {
            float p = (st[qh][c][j] > -1e29f) ? __expf(st[qh][c][j] - m_r[qh]) : 0.f;
            ps += p;
            pk.hh[j] = (__bf16)p;
          }
          *(ushort4*)(pl + (qh * 16 + fr) * 128 + ((c * 32 + hi * 8) ^ swz)) = pk.u4;
        }
      }
      ps += __shfl_xor(ps, 16, 64);
      ps += __shfl_xor(ps, 32, 64);
      l_r[qh] = l_r[qh] * fac + ps;
      if (need) {
        float fq0 = __shfl(fac, hi * 4 + 0, 64);
        float fq1 = __shfl(fac, hi * 4 + 1, 64);
        float fq2 = __shfl(fac, hi * 4 + 2, 64);
        float fq3 = __shfl(fac, hi * 4 + 3, 64);
#pragma unroll
        for (int n = 0; n < 8; ++n) {
          acc_o[qh][n][0] *= fq0; acc_o[qh][n][1] *= fq1;
          acc_o[qh][n][2] *= fq2; acc_o[qh][n][3] *= fq3;
        }
      }
    }

    // ---- PV: vf shared across both Q-halves ----
#pragma unroll
    for (int ch = 0; ch < 2; ++ch) {
      bf16x8 pa0 = *(const bf16x8*)(pl + fr * 128 + ((ch * 64 + hi * 16) ^ swz));
      bf16x8 pa1 = *(const bf16x8*)(pl + (16 + fr) * 128 + ((ch * 64 + hi * 16) ^ swz));
      __builtin_amdgcn_s_setprio(1);
#pragma unroll
      for (int n = 0; n < 8; ++n) {
        int row = n * 16 + fr;
        bf16x8 vf = *(const bf16x8*)(vb + row * 128 + ((ch * 64 + hi * 16) ^ swz));
        acc_o[0][n] = __builtin_amdgcn_mfma_f32_16x16x32_bf16(pa0, vf, acc_o[0][n], 0, 0, 0);
        acc_o[1][n] = __builtin_amdgcn_mfma_f32_16x16x32_bf16(pa1, vf, acc_o[1][n], 0, 0, 0);
      }
      __builtin_amdgcn_s_setprio(0);
    }
    cur ^= 1;
  }

  // ---- epilogue ----
#pragma unroll
  for (int qh = 0; qh < 2; ++qh) {
    float inv = 1.f / l_r[qh];
    float iq[4];
#pragma unroll
    for (int j = 0; j < 4; ++j) iq[j] = __shfl(inv, hi * 4 + j, 64);
#pragma unroll
    for (int n = 0; n < 8; ++n)
#pragma unroll
      for (int jj = 0; jj < 4; ++jj) {
        int t = t0w + qh * 16 + hi * 4 + jj;
        ybf[((size_t)(b * T_ + t)) * (NH_*HS_) + h * HS_ + n * 16 + fr] =
            f2bf(acc_o[qh][n][jj] * iq[jj]);
      }
  }
}

extern "C" void kernel_launch(void* const* d_in, const int* in_sizes, int n_in,
                              void* d_out, int out_size, void* d_ws, size_t ws_size,
                              hipStream_t stream) {
  (void)in_sizes; (void)n_in; (void)out_size;
  const float* x     = (const float*)d_in[0];
  const float* Wqkv  = (const float*)d_in[1];
  const float* Wproj = (const float*)d_in[2];
  const float* qw    = (const float*)d_in[3];
  const float* kw    = (const float*)d_in[4];
  const float* vw    = (const float*)d_in[5];
  const float* cosT  = (const float*)d_in[6];
  const float* sinT  = (const float*)d_in[7];
  float* out = (float*)d_out;
  char* ws = (char*)d_ws;

  // workspace layout (bytes)
  u16* x_bf    = (u16*)(ws + 0);          // 16,777,216
  u16* wqkv_t  = (u16*)(ws + 16777216);   // 12,582,912
  u16* wproj_t = (u16*)(ws + 29360128);   //  8,388,608
  u16* qkv_bf  = (u16*)(ws + 37748736);   // 25,165,824
  u16* q_bf    = (u16*)(ws + 62914560);   // 16,777,216
  u16* k_bf    = (u16*)(ws + 79691776);   //  4,194,304
  u16* v_tmp   = (u16*)(ws + 83886080);   //  4,194,304
  u16* v_t     = (u16*)(ws + 88080384);   //  4,194,304
  u16* y_bf    = (u16*)(ws + 92274688);   // 16,777,216
  if (ws_size < (size_t)109051904) return;

  prep_all<<<18432, 256, 0, stream>>>(x, Wqkv, Wproj, x_bf, wqkv_t, wproj_t);
  gemm_bt<3072, 2048, 1><<<dim3(32, 24), 256, 0, stream>>>(x_bf, wqkv_t, qkv_bf, nullptr);
  conv_all<<<3072, 256, 0, stream>>>(qkv_bf, qw, kw, vw, cosT, sinT, q_bf, k_bf, v_tmp);
  transpose_v16<<<dim3(16, 64, 2), 256, 0, stream>>>(v_tmp, v_t);
  attn_swin<<<512, 256, 0, stream>>>(q_bf, k_bf, v_t, y_bf);
  gemm_bt<2048, 2048, 0><<<dim3(32, 16), 256, 0, stream>>>(y_bf, wproj_t, nullptr, out);
}